// Round 5
// baseline (336.712 us; speedup 1.0000x reference)
//
#include <hip/hip_runtime.h>

// VectorQuantizer: N=131072 tokens, D=64, K=1024 codes.
// out (f32 concat): [0,8388608) quant, [8388608] loss, [8388609,...) idx.
//
// R5: R4 counters: dist MfmaUtil 26 / VALU 34 / Occ 20% -> stall-bound at
// 2 waves/SIMD (64KB LDS = 2 blocks/CU), and ~103 us hides outside dist
// (combine: grid-limited gather + a redundant 33MB x re-read).
// Fixes: (a) NQ=8 -> 32KB LDS staging, launch_bounds(256,4) -> ~5 blocks/CU
// (~20 waves/CU); (b) combine drops x entirely - the loss term is decoded
// from the packed u64 key (high word = sortable min distance), 4 lanes per
// token -> 2048 blocks, pure L2 gather + coalesced write.
// Distance math unchanged from R4 (passed): fp16 split-product MFMA
// (hi*hi + hi*lo + lo*hi), np8 x2/e2, s = fma(-2,dot,x2+e2), packed-u64
// atomicMin merge == ascending-k first-min.

#define KC 1024
#define DD 64
#define NTOK (32 * 4096)
#define NQ 8
#define QUANT_ELEMS ((size_t)NTOK * DD)        // 8388608
#define LOSS_OFF QUANT_ELEMS
#define IDX_OFF (QUANT_ELEMS + 1)

// ws float-word offsets
#define WS_E2 0                      // 1024 f32
#define WS_LOSS 1024                 // 1 f32
#define WS_X2 2048                   // NTOK f32
#define WS_PACKED_F (2048 + NTOK)    // NTOK u64
#define WS_BFRAG_F (WS_PACKED_F + 2 * NTOK)  // 64 tiles*4 frags*64 lanes*16B

typedef _Float16 f16x8 __attribute__((ext_vector_type(8)));
typedef float f32x4 __attribute__((ext_vector_type(4)));

__device__ __forceinline__ unsigned int sortable_bits(float f) {
  unsigned int b = __float_as_uint(f);
  return b ^ (unsigned int)(((int)b >> 31) | 0x80000000);
}

// np pairwise-8 sum of squares of a 64-float row
__device__ __forceinline__ float row_sumsq_np8(const float* p) {
  float r[8];
#pragma unroll
  for (int j = 0; j < 8; ++j) r[j] = p[j] * p[j];
#pragma unroll
  for (int i = 1; i < 8; ++i)
#pragma unroll
    for (int j = 0; j < 8; ++j) {
      float v = p[i * 8 + j];
      r[j] += v * v;
    }
  return ((r[0] + r[1]) + (r[2] + r[3])) + ((r[4] + r[5]) + (r[6] + r[7]));
}

// blocks [0,512): x2 + packed init; [512,576): B-frag build; [576,580): e2
__global__ void vq_setup(const float* __restrict__ x_in,
                         const float* __restrict__ emb,
                         float* __restrict__ ws) {
  const int b = blockIdx.x;
  const int tid = threadIdx.x;
  if (b < 512) {
    const int t = b * 256 + tid;
    ((unsigned long long*)(ws + WS_PACKED_F))[t] = ~0ULL;
    if (t == 0) ws[WS_LOSS] = 0.0f;
    ws[WS_X2 + t] = row_sumsq_np8(x_in + (size_t)t * DD);
  } else if (b < 576) {
    const int nt = b - 512;            // global tile 0..63 (16 codes each)
    const int f = tid >> 6;            // 0..3: plane(hi/lo) x kstep
    const int lane = tid & 63;
    const int plane = f >> 1, ks = f & 1;
    const int n = nt * 16 + (lane & 15);
    const int kb = ks * 32 + ((lane >> 4) & 3) * 8;
    const float* ep = emb + (size_t)n * DD + kb;
    f16x8 o;
#pragma unroll
    for (int j = 0; j < 8; ++j) {
      float v = ep[j];
      _Float16 h = (_Float16)v;
      o[j] = (plane == 0) ? h : (_Float16)(v - (float)h);
    }
    ((f16x8*)(ws + WS_BFRAG_F))[(nt * 4 + f) * 64 + lane] = o;
  } else {
    const int k = (b - 576) * 256 + tid;  // 0..1023
    ws[WS_E2 + k] = row_sumsq_np8(emb + (size_t)k * DD);
  }
}

__launch_bounds__(256, 4)
__global__ void vq_dist_mfma(const float* __restrict__ x_in,
                             const float* __restrict__ ws_ro,
                             unsigned long long* __restrict__ packed) {
  const int tid = threadIdx.x;
  const int wave = tid >> 6, lane = tid & 63;
  const int quad = lane >> 4, l16 = lane & 15;
  const int q = blockIdx.y;                       // code eighth (128 codes)
  const int tokBase = blockIdx.x * 256 + wave * 64;

  const float* x2g = ws_ro + WS_X2;
  const float* e2g = ws_ro + WS_E2;

  // Stage this eighth's B fragments: 8 tiles * 4 frags * 64 lanes * 16B = 32KB
  __shared__ float4 Bf[2048];
  {
    const float4* bsrc = (const float4*)(ws_ro + WS_BFRAG_F) + (size_t)q * 2048;
#pragma unroll
    for (int i = 0; i < 8; ++i) {
      int slot = i * 256 + tid;
      Bf[slot] = bsrc[slot];
    }
  }

  // A fragments: 4 m-sets of 16 tokens; split x into fp16 hi/lo planes.
  f16x8 ah[4][2], al[4][2];
#pragma unroll
  for (int ms = 0; ms < 4; ++ms) {
    const float* xr = x_in + (size_t)(tokBase + ms * 16 + l16) * DD;
#pragma unroll
    for (int ks = 0; ks < 2; ++ks) {
      const float4* p = (const float4*)(xr + ks * 32 + quad * 8);
      float4 v0 = p[0], v1 = p[1];
      float vv[8] = {v0.x, v0.y, v0.z, v0.w, v1.x, v1.y, v1.z, v1.w};
#pragma unroll
      for (int j = 0; j < 8; ++j) {
        _Float16 h = (_Float16)vv[j];
        ah[ms][ks][j] = h;
        al[ms][ks][j] = (_Float16)(vv[j] - (float)h);
      }
    }
  }

  // x2 for this lane's C rows; e2 for this lane's 8 code columns
  float x2v[4][4];
#pragma unroll
  for (int ms = 0; ms < 4; ++ms)
#pragma unroll
    for (int r = 0; r < 4; ++r)
      x2v[ms][r] = x2g[tokBase + ms * 16 + quad * 4 + r];
  float e2pre[8];
#pragma unroll
  for (int nt = 0; nt < 8; ++nt) e2pre[nt] = e2g[q * 128 + nt * 16 + l16];

  __syncthreads();  // Bf ready; no barriers after this

  float best[4][4];
  int bidx[4][4];
#pragma unroll
  for (int ms = 0; ms < 4; ++ms)
#pragma unroll
    for (int r = 0; r < 4; ++r) { best[ms][r] = 3.402823466e38f; bidx[ms][r] = 0; }

  const f16x8* bfp = (const f16x8*)Bf;
#pragma unroll
  for (int nt = 0; nt < 8; ++nt) {
    const int ch = nt * 4;
    f16x8 bh0 = bfp[(ch + 0) * 64 + lane];
    f16x8 bh1 = bfp[(ch + 1) * 64 + lane];
    f16x8 bl0 = bfp[(ch + 2) * 64 + lane];
    f16x8 bl1 = bfp[(ch + 3) * 64 + lane];
    const int ncur = q * 128 + nt * 16 + l16;     // this lane's code column
    const float e2v = e2pre[nt];
#pragma unroll
    for (int ms = 0; ms < 4; ++ms) {
      f32x4 acc = {0.f, 0.f, 0.f, 0.f};
      acc = __builtin_amdgcn_mfma_f32_16x16x32_f16(ah[ms][0], bh0, acc, 0, 0, 0);
      acc = __builtin_amdgcn_mfma_f32_16x16x32_f16(ah[ms][1], bh1, acc, 0, 0, 0);
      acc = __builtin_amdgcn_mfma_f32_16x16x32_f16(al[ms][0], bh0, acc, 0, 0, 0);
      acc = __builtin_amdgcn_mfma_f32_16x16x32_f16(al[ms][1], bh1, acc, 0, 0, 0);
      acc = __builtin_amdgcn_mfma_f32_16x16x32_f16(ah[ms][0], bl0, acc, 0, 0, 0);
      acc = __builtin_amdgcn_mfma_f32_16x16x32_f16(ah[ms][1], bl1, acc, 0, 0, 0);
#pragma unroll
      for (int r = 0; r < 4; ++r) {
        float s = __builtin_fmaf(-2.0f, acc[r], x2v[ms][r] + e2v);
        if (s < best[ms][r]) { best[ms][r] = s; bidx[ms][r] = ncur; }
      }
    }
  }

  // Reduce across the 16 lanes of each quad (packed key: min == first-min).
#pragma unroll
  for (int ms = 0; ms < 4; ++ms)
#pragma unroll
    for (int r = 0; r < 4; ++r) {
      unsigned long long key =
          ((unsigned long long)sortable_bits(best[ms][r]) << 32) |
          (unsigned int)bidx[ms][r];
#pragma unroll
      for (int m = 1; m < 16; m <<= 1) {
        unsigned long long o = __shfl_xor(key, m);
        key = o < key ? o : key;
      }
      if (l16 == 0)
        atomicMin(&packed[tokBase + ms * 16 + quad * 4 + r], key);
    }
}

// 4 lanes per token: gather winning e-row, write quant+idx, loss from key.
__global__ void vq_combine(const float* __restrict__ emb,
                           const unsigned long long* __restrict__ packed,
                           float* __restrict__ out,
                           float* __restrict__ loss_acc) {
  const int tid = threadIdx.x;
  const int token = blockIdx.x * 64 + (tid >> 2);
  const int part = tid & 3;

  const unsigned long long key = packed[token];
  const int bidx = (int)(unsigned int)key;

  float err = 0.0f;
  if (part == 0) {
    out[IDX_OFF + (size_t)token] = (float)bidx;
    unsigned int u = (unsigned int)(key >> 32);
    unsigned int fb = (u & 0x80000000u) ? (u ^ 0x80000000u) : ~u;
    err = __uint_as_float(fb);  // min distance == |x - e|^2 (expanded form)
  }

  const float4* eq = (const float4*)(emb + (size_t)bidx * DD) + part * 4;
  float4* op = (float4*)(out + (size_t)token * DD) + part * 4;
  float4 v0 = eq[0], v1 = eq[1], v2 = eq[2], v3 = eq[3];
  op[0] = v0; op[1] = v1; op[2] = v2; op[3] = v3;

#pragma unroll
  for (int off = 32; off > 0; off >>= 1) err += __shfl_down(err, off);
  __shared__ float wsum[4];
  const int wid = tid >> 6;
  if ((tid & 63) == 0) wsum[wid] = err;
  __syncthreads();
  if (tid == 0)
    atomicAdd(loss_acc, (wsum[0] + wsum[1]) + (wsum[2] + wsum[3]));
}

__global__ void vq_finish(const float* __restrict__ acc, float* __restrict__ out) {
  float m = acc[0] / (float)QUANT_ELEMS;
  out[LOSS_OFF] = m + 0.25f * m;  // q_latent + COMMITMENT_COST * e_latent
}

extern "C" void kernel_launch(void* const* d_in, const int* in_sizes, int n_in,
                              void* d_out, int out_size, void* d_ws, size_t ws_size,
                              hipStream_t stream) {
  const float* x = (const float*)d_in[0];
  const float* emb = (const float*)d_in[1];
  float* out = (float*)d_out;
  float* ws = (float*)d_ws;
  unsigned long long* packed = (unsigned long long*)(ws + WS_PACKED_F);

  vq_setup<<<580, 256, 0, stream>>>(x, emb, ws);
  dim3 gdist(NTOK / 256, NQ);
  vq_dist_mfma<<<gdist, 256, 0, stream>>>(x, ws, packed);
  vq_combine<<<NTOK / 64, 256, 0, stream>>>(emb, packed, out, ws + WS_LOSS);
  vq_finish<<<1, 1, 0, stream>>>(ws + WS_LOSS, out);
}

// Round 6
// 264.801 us; speedup vs baseline: 1.2716x; 1.2716x over previous
//
#include <hip/hip_runtime.h>

// VectorQuantizer: N=131072 tokens, D=64, K=1024 codes.
// out (f32 concat): [0,8388608) quant, [8388608] loss, [8388609,...) idx.
//
// R6: R5's launch_bounds(256,4) capped VGPR at 64 -> A-frags spilled ->
// 875 MB/dispatch of scratch traffic (FETCH 400MB/WRITE 475MB), dist 250us.
// Revert to (256,2) (R4-proven: 88 VGPR, zero spill) while KEEPING NQ=8 /
// 32KB LDS: VGPR<=128 allows 4 waves/SIMD, LDS allows 5 blocks/CU -> expect
// ~4 blocks/CU (vs R4's LDS-capped 2). vq_finish folded into vq_combine via
// device-scope completion counter (one fewer dispatch).
// Distance math unchanged since R4 (passed): fp16 split-product MFMA
// (hi*hi + hi*lo + lo*hi), np8 x2/e2, s = fma(-2,dot,x2+e2), packed-u64
// atomicMin merge == ascending-k first-min; loss decoded from min-dist key.

#define KC 1024
#define DD 64
#define NTOK (32 * 4096)
#define NQ 8
#define QUANT_ELEMS ((size_t)NTOK * DD)        // 8388608
#define LOSS_OFF QUANT_ELEMS
#define IDX_OFF (QUANT_ELEMS + 1)

// ws float-word offsets
#define WS_E2 0                      // 1024 f32
#define WS_LOSS 1024                 // 1 f32
#define WS_CNT 1025                  // 1 u32 (completion counter)
#define WS_X2 2048                   // NTOK f32
#define WS_PACKED_F (2048 + NTOK)    // NTOK u64
#define WS_BFRAG_F (WS_PACKED_F + 2 * NTOK)  // 64 tiles*4 frags*64 lanes*16B

#define COMBINE_BLOCKS (NTOK / 64)   // 2048

typedef _Float16 f16x8 __attribute__((ext_vector_type(8)));
typedef float f32x4 __attribute__((ext_vector_type(4)));

__device__ __forceinline__ unsigned int sortable_bits(float f) {
  unsigned int b = __float_as_uint(f);
  return b ^ (unsigned int)(((int)b >> 31) | 0x80000000);
}

// np pairwise-8 sum of squares of a 64-float row
__device__ __forceinline__ float row_sumsq_np8(const float* p) {
  float r[8];
#pragma unroll
  for (int j = 0; j < 8; ++j) r[j] = p[j] * p[j];
#pragma unroll
  for (int i = 1; i < 8; ++i)
#pragma unroll
    for (int j = 0; j < 8; ++j) {
      float v = p[i * 8 + j];
      r[j] += v * v;
    }
  return ((r[0] + r[1]) + (r[2] + r[3])) + ((r[4] + r[5]) + (r[6] + r[7]));
}

// blocks [0,512): x2 + packed init; [512,576): B-frag build; [576,580): e2
__global__ void vq_setup(const float* __restrict__ x_in,
                         const float* __restrict__ emb,
                         float* __restrict__ ws) {
  const int b = blockIdx.x;
  const int tid = threadIdx.x;
  if (b < 512) {
    const int t = b * 256 + tid;
    ((unsigned long long*)(ws + WS_PACKED_F))[t] = ~0ULL;
    if (t == 0) ws[WS_LOSS] = 0.0f;
    if (t == 1) ((unsigned int*)ws)[WS_CNT] = 0u;
    ws[WS_X2 + t] = row_sumsq_np8(x_in + (size_t)t * DD);
  } else if (b < 576) {
    const int nt = b - 512;            // global tile 0..63 (16 codes each)
    const int f = tid >> 6;            // 0..3: plane(hi/lo) x kstep
    const int lane = tid & 63;
    const int plane = f >> 1, ks = f & 1;
    const int n = nt * 16 + (lane & 15);
    const int kb = ks * 32 + ((lane >> 4) & 3) * 8;
    const float* ep = emb + (size_t)n * DD + kb;
    f16x8 o;
#pragma unroll
    for (int j = 0; j < 8; ++j) {
      float v = ep[j];
      _Float16 h = (_Float16)v;
      o[j] = (plane == 0) ? h : (_Float16)(v - (float)h);
    }
    ((f16x8*)(ws + WS_BFRAG_F))[(nt * 4 + f) * 64 + lane] = o;
  } else {
    const int k = (b - 576) * 256 + tid;  // 0..1023
    ws[WS_E2 + k] = row_sumsq_np8(emb + (size_t)k * DD);
  }
}

__launch_bounds__(256, 2)
__global__ void vq_dist_mfma(const float* __restrict__ x_in,
                             const float* __restrict__ ws_ro,
                             unsigned long long* __restrict__ packed) {
  const int tid = threadIdx.x;
  const int wave = tid >> 6, lane = tid & 63;
  const int quad = lane >> 4, l16 = lane & 15;
  const int q = blockIdx.y;                       // code eighth (128 codes)
  const int tokBase = blockIdx.x * 256 + wave * 64;

  const float* x2g = ws_ro + WS_X2;
  const float* e2g = ws_ro + WS_E2;

  // Stage this eighth's B fragments: 8 tiles * 4 frags * 64 lanes * 16B = 32KB
  __shared__ float4 Bf[2048];
  {
    const float4* bsrc = (const float4*)(ws_ro + WS_BFRAG_F) + (size_t)q * 2048;
#pragma unroll
    for (int i = 0; i < 8; ++i) {
      int slot = i * 256 + tid;
      Bf[slot] = bsrc[slot];
    }
  }

  // A fragments: 4 m-sets of 16 tokens; split x into fp16 hi/lo planes.
  f16x8 ah[4][2], al[4][2];
#pragma unroll
  for (int ms = 0; ms < 4; ++ms) {
    const float* xr = x_in + (size_t)(tokBase + ms * 16 + l16) * DD;
#pragma unroll
    for (int ks = 0; ks < 2; ++ks) {
      const float4* p = (const float4*)(xr + ks * 32 + quad * 8);
      float4 v0 = p[0], v1 = p[1];
      float vv[8] = {v0.x, v0.y, v0.z, v0.w, v1.x, v1.y, v1.z, v1.w};
#pragma unroll
      for (int j = 0; j < 8; ++j) {
        _Float16 h = (_Float16)vv[j];
        ah[ms][ks][j] = h;
        al[ms][ks][j] = (_Float16)(vv[j] - (float)h);
      }
    }
  }

  // x2 for this lane's C rows; e2 for this lane's 8 code columns
  float x2v[4][4];
#pragma unroll
  for (int ms = 0; ms < 4; ++ms)
#pragma unroll
    for (int r = 0; r < 4; ++r)
      x2v[ms][r] = x2g[tokBase + ms * 16 + quad * 4 + r];
  float e2pre[8];
#pragma unroll
  for (int nt = 0; nt < 8; ++nt) e2pre[nt] = e2g[q * 128 + nt * 16 + l16];

  __syncthreads();  // Bf ready; no barriers after this

  float best[4][4];
  int bidx[4][4];
#pragma unroll
  for (int ms = 0; ms < 4; ++ms)
#pragma unroll
    for (int r = 0; r < 4; ++r) { best[ms][r] = 3.402823466e38f; bidx[ms][r] = 0; }

  const f16x8* bfp = (const f16x8*)Bf;
#pragma unroll
  for (int nt = 0; nt < 8; ++nt) {
    const int ch = nt * 4;
    f16x8 bh0 = bfp[(ch + 0) * 64 + lane];
    f16x8 bh1 = bfp[(ch + 1) * 64 + lane];
    f16x8 bl0 = bfp[(ch + 2) * 64 + lane];
    f16x8 bl1 = bfp[(ch + 3) * 64 + lane];
    const int ncur = q * 128 + nt * 16 + l16;     // this lane's code column
    const float e2v = e2pre[nt];
#pragma unroll
    for (int ms = 0; ms < 4; ++ms) {
      f32x4 acc = {0.f, 0.f, 0.f, 0.f};
      acc = __builtin_amdgcn_mfma_f32_16x16x32_f16(ah[ms][0], bh0, acc, 0, 0, 0);
      acc = __builtin_amdgcn_mfma_f32_16x16x32_f16(ah[ms][1], bh1, acc, 0, 0, 0);
      acc = __builtin_amdgcn_mfma_f32_16x16x32_f16(al[ms][0], bh0, acc, 0, 0, 0);
      acc = __builtin_amdgcn_mfma_f32_16x16x32_f16(al[ms][1], bh1, acc, 0, 0, 0);
      acc = __builtin_amdgcn_mfma_f32_16x16x32_f16(ah[ms][0], bl0, acc, 0, 0, 0);
      acc = __builtin_amdgcn_mfma_f32_16x16x32_f16(ah[ms][1], bl1, acc, 0, 0, 0);
#pragma unroll
      for (int r = 0; r < 4; ++r) {
        float s = __builtin_fmaf(-2.0f, acc[r], x2v[ms][r] + e2v);
        if (s < best[ms][r]) { best[ms][r] = s; bidx[ms][r] = ncur; }
      }
    }
  }

  // Reduce across the 16 lanes of each quad (packed key: min == first-min).
#pragma unroll
  for (int ms = 0; ms < 4; ++ms)
#pragma unroll
    for (int r = 0; r < 4; ++r) {
      unsigned long long key =
          ((unsigned long long)sortable_bits(best[ms][r]) << 32) |
          (unsigned int)bidx[ms][r];
#pragma unroll
      for (int m = 1; m < 16; m <<= 1) {
        unsigned long long o = __shfl_xor(key, m);
        key = o < key ? o : key;
      }
      if (l16 == 0)
        atomicMin(&packed[tokBase + ms * 16 + quad * 4 + r], key);
    }
}

// 4 lanes per token: gather winning e-row, write quant+idx, loss from key.
// Last block to finish also writes out[LOSS_OFF] (completion counter).
__global__ void vq_combine(const float* __restrict__ emb,
                           const unsigned long long* __restrict__ packed,
                           float* __restrict__ out,
                           float* __restrict__ loss_acc,
                           unsigned int* __restrict__ cnt) {
  const int tid = threadIdx.x;
  const int token = blockIdx.x * 64 + (tid >> 2);
  const int part = tid & 3;

  const unsigned long long key = packed[token];
  const int bidx = (int)(unsigned int)key;

  float err = 0.0f;
  if (part == 0) {
    out[IDX_OFF + (size_t)token] = (float)bidx;
    unsigned int u = (unsigned int)(key >> 32);
    unsigned int fb = (u & 0x80000000u) ? (u ^ 0x80000000u) : ~u;
    err = __uint_as_float(fb);  // min distance == |x - e|^2 (expanded form)
  }

  const float4* eq = (const float4*)(emb + (size_t)bidx * DD) + part * 4;
  float4* op = (float4*)(out + (size_t)token * DD) + part * 4;
  float4 v0 = eq[0], v1 = eq[1], v2 = eq[2], v3 = eq[3];
  op[0] = v0; op[1] = v1; op[2] = v2; op[3] = v3;

#pragma unroll
  for (int off = 32; off > 0; off >>= 1) err += __shfl_down(err, off);
  __shared__ float wsum[4];
  const int wid = tid >> 6;
  if ((tid & 63) == 0) wsum[wid] = err;
  __syncthreads();
  if (tid == 0) {
    atomicAdd(loss_acc, (wsum[0] + wsum[1]) + (wsum[2] + wsum[3]));
    __threadfence();  // make our add visible before signaling completion
    unsigned int done = atomicAdd(cnt, 1u);
    if (done == COMBINE_BLOCKS - 1) {
      float total = atomicAdd(loss_acc, 0.0f);  // coherent device-scope read
      float m = total / (float)QUANT_ELEMS;
      out[LOSS_OFF] = m + 0.25f * m;  // q_latent + COMMITMENT_COST * e_latent
    }
  }
}

extern "C" void kernel_launch(void* const* d_in, const int* in_sizes, int n_in,
                              void* d_out, int out_size, void* d_ws, size_t ws_size,
                              hipStream_t stream) {
  const float* x = (const float*)d_in[0];
  const float* emb = (const float*)d_in[1];
  float* out = (float*)d_out;
  float* ws = (float*)d_ws;
  unsigned long long* packed = (unsigned long long*)(ws + WS_PACKED_F);

  vq_setup<<<580, 256, 0, stream>>>(x, emb, ws);
  dim3 gdist(NTOK / 256, NQ);
  vq_dist_mfma<<<gdist, 256, 0, stream>>>(x, ws, packed);
  vq_combine<<<COMBINE_BLOCKS, 256, 0, stream>>>(emb, packed, out, ws + WS_LOSS,
                                                 ((unsigned int*)ws) + WS_CNT);
}

// Round 7
// 178.824 us; speedup vs baseline: 1.8829x; 1.4808x over previous
//
#include <hip/hip_runtime.h>

// VectorQuantizer: N=131072 tokens, D=64, K=1024 codes.
// out (f32 concat): [0,8388608) quant, [8388608] loss, [8388609,...) idx.
//
// R7: R6's combine was 137us with VALUBusy 0.5% — 2048 blocks serialized
// through TWO same-address device-scope atomics (loss_acc + completion cnt,
// 67ns/block retire). Fix: per-block partial loss -> blocksum[blockIdx]
// (plain stores, zero contention), separate 1-block vq_finish reduces 2048
// partials. dist/setup identical to R6 (passed).
// Distance math unchanged since R4: fp16 split-product MFMA
// (hi*hi + hi*lo + lo*hi), np8 x2/e2, s = fma(-2,dot,x2+e2), packed-u64
// atomicMin merge == ascending-k first-min; loss decoded from min-dist key.

#define KC 1024
#define DD 64
#define NTOK (32 * 4096)
#define NQ 8
#define QUANT_ELEMS ((size_t)NTOK * DD)        // 8388608
#define LOSS_OFF QUANT_ELEMS
#define IDX_OFF (QUANT_ELEMS + 1)

// ws float-word offsets
#define WS_E2 0                      // 1024 f32
#define WS_X2 2048                   // NTOK f32
#define WS_PACKED_F (2048 + NTOK)    // NTOK u64
#define WS_BFRAG_F (WS_PACKED_F + 2 * NTOK)  // 16384 f16x8 = 65536 f32 words
#define WS_BSUM (WS_BFRAG_F + 65536) // 2048 f32 per-block loss partials

#define COMBINE_BLOCKS (NTOK / 64)   // 2048

typedef _Float16 f16x8 __attribute__((ext_vector_type(8)));
typedef float f32x4 __attribute__((ext_vector_type(4)));

__device__ __forceinline__ unsigned int sortable_bits(float f) {
  unsigned int b = __float_as_uint(f);
  return b ^ (unsigned int)(((int)b >> 31) | 0x80000000);
}

// np pairwise-8 sum of squares of a 64-float row
__device__ __forceinline__ float row_sumsq_np8(const float* p) {
  float r[8];
#pragma unroll
  for (int j = 0; j < 8; ++j) r[j] = p[j] * p[j];
#pragma unroll
  for (int i = 1; i < 8; ++i)
#pragma unroll
    for (int j = 0; j < 8; ++j) {
      float v = p[i * 8 + j];
      r[j] += v * v;
    }
  return ((r[0] + r[1]) + (r[2] + r[3])) + ((r[4] + r[5]) + (r[6] + r[7]));
}

// blocks [0,512): x2 + packed init; [512,576): B-frag build; [576,580): e2
__global__ void vq_setup(const float* __restrict__ x_in,
                         const float* __restrict__ emb,
                         float* __restrict__ ws) {
  const int b = blockIdx.x;
  const int tid = threadIdx.x;
  if (b < 512) {
    const int t = b * 256 + tid;
    ((unsigned long long*)(ws + WS_PACKED_F))[t] = ~0ULL;
    ws[WS_X2 + t] = row_sumsq_np8(x_in + (size_t)t * DD);
  } else if (b < 576) {
    const int nt = b - 512;            // global tile 0..63 (16 codes each)
    const int f = tid >> 6;            // 0..3: plane(hi/lo) x kstep
    const int lane = tid & 63;
    const int plane = f >> 1, ks = f & 1;
    const int n = nt * 16 + (lane & 15);
    const int kb = ks * 32 + ((lane >> 4) & 3) * 8;
    const float* ep = emb + (size_t)n * DD + kb;
    f16x8 o;
#pragma unroll
    for (int j = 0; j < 8; ++j) {
      float v = ep[j];
      _Float16 h = (_Float16)v;
      o[j] = (plane == 0) ? h : (_Float16)(v - (float)h);
    }
    ((f16x8*)(ws + WS_BFRAG_F))[(nt * 4 + f) * 64 + lane] = o;
  } else {
    const int k = (b - 576) * 256 + tid;  // 0..1023
    ws[WS_E2 + k] = row_sumsq_np8(emb + (size_t)k * DD);
  }
}

__launch_bounds__(256, 2)
__global__ void vq_dist_mfma(const float* __restrict__ x_in,
                             const float* __restrict__ ws_ro,
                             unsigned long long* __restrict__ packed) {
  const int tid = threadIdx.x;
  const int wave = tid >> 6, lane = tid & 63;
  const int quad = lane >> 4, l16 = lane & 15;
  const int q = blockIdx.y;                       // code eighth (128 codes)
  const int tokBase = blockIdx.x * 256 + wave * 64;

  const float* x2g = ws_ro + WS_X2;
  const float* e2g = ws_ro + WS_E2;

  // Stage this eighth's B fragments: 8 tiles * 4 frags * 64 lanes * 16B = 32KB
  __shared__ float4 Bf[2048];
  {
    const float4* bsrc = (const float4*)(ws_ro + WS_BFRAG_F) + (size_t)q * 2048;
#pragma unroll
    for (int i = 0; i < 8; ++i) {
      int slot = i * 256 + tid;
      Bf[slot] = bsrc[slot];
    }
  }

  // A fragments: 4 m-sets of 16 tokens; split x into fp16 hi/lo planes.
  f16x8 ah[4][2], al[4][2];
#pragma unroll
  for (int ms = 0; ms < 4; ++ms) {
    const float* xr = x_in + (size_t)(tokBase + ms * 16 + l16) * DD;
#pragma unroll
    for (int ks = 0; ks < 2; ++ks) {
      const float4* p = (const float4*)(xr + ks * 32 + quad * 8);
      float4 v0 = p[0], v1 = p[1];
      float vv[8] = {v0.x, v0.y, v0.z, v0.w, v1.x, v1.y, v1.z, v1.w};
#pragma unroll
      for (int j = 0; j < 8; ++j) {
        _Float16 h = (_Float16)vv[j];
        ah[ms][ks][j] = h;
        al[ms][ks][j] = (_Float16)(vv[j] - (float)h);
      }
    }
  }

  // x2 for this lane's C rows; e2 for this lane's 8 code columns
  float x2v[4][4];
#pragma unroll
  for (int ms = 0; ms < 4; ++ms)
#pragma unroll
    for (int r = 0; r < 4; ++r)
      x2v[ms][r] = x2g[tokBase + ms * 16 + quad * 4 + r];
  float e2pre[8];
#pragma unroll
  for (int nt = 0; nt < 8; ++nt) e2pre[nt] = e2g[q * 128 + nt * 16 + l16];

  __syncthreads();  // Bf ready; no barriers after this

  float best[4][4];
  int bidx[4][4];
#pragma unroll
  for (int ms = 0; ms < 4; ++ms)
#pragma unroll
    for (int r = 0; r < 4; ++r) { best[ms][r] = 3.402823466e38f; bidx[ms][r] = 0; }

  const f16x8* bfp = (const f16x8*)Bf;
#pragma unroll
  for (int nt = 0; nt < 8; ++nt) {
    const int ch = nt * 4;
    f16x8 bh0 = bfp[(ch + 0) * 64 + lane];
    f16x8 bh1 = bfp[(ch + 1) * 64 + lane];
    f16x8 bl0 = bfp[(ch + 2) * 64 + lane];
    f16x8 bl1 = bfp[(ch + 3) * 64 + lane];
    const int ncur = q * 128 + nt * 16 + l16;     // this lane's code column
    const float e2v = e2pre[nt];
#pragma unroll
    for (int ms = 0; ms < 4; ++ms) {
      f32x4 acc = {0.f, 0.f, 0.f, 0.f};
      acc = __builtin_amdgcn_mfma_f32_16x16x32_f16(ah[ms][0], bh0, acc, 0, 0, 0);
      acc = __builtin_amdgcn_mfma_f32_16x16x32_f16(ah[ms][1], bh1, acc, 0, 0, 0);
      acc = __builtin_amdgcn_mfma_f32_16x16x32_f16(al[ms][0], bh0, acc, 0, 0, 0);
      acc = __builtin_amdgcn_mfma_f32_16x16x32_f16(al[ms][1], bh1, acc, 0, 0, 0);
      acc = __builtin_amdgcn_mfma_f32_16x16x32_f16(ah[ms][0], bl0, acc, 0, 0, 0);
      acc = __builtin_amdgcn_mfma_f32_16x16x32_f16(ah[ms][1], bl1, acc, 0, 0, 0);
#pragma unroll
      for (int r = 0; r < 4; ++r) {
        float s = __builtin_fmaf(-2.0f, acc[r], x2v[ms][r] + e2v);
        if (s < best[ms][r]) { best[ms][r] = s; bidx[ms][r] = ncur; }
      }
    }
  }

  // Reduce across the 16 lanes of each quad (packed key: min == first-min).
#pragma unroll
  for (int ms = 0; ms < 4; ++ms)
#pragma unroll
    for (int r = 0; r < 4; ++r) {
      unsigned long long key =
          ((unsigned long long)sortable_bits(best[ms][r]) << 32) |
          (unsigned int)bidx[ms][r];
#pragma unroll
      for (int m = 1; m < 16; m <<= 1) {
        unsigned long long o = __shfl_xor(key, m);
        key = o < key ? o : key;
      }
      if (l16 == 0)
        atomicMin(&packed[tokBase + ms * 16 + quad * 4 + r], key);
    }
}

// 4 lanes per token: gather winning e-row, write quant+idx, loss from key.
// Per-block loss partial -> blocksum[blockIdx.x]; NO contended atomics.
__global__ void vq_combine(const float* __restrict__ emb,
                           const unsigned long long* __restrict__ packed,
                           float* __restrict__ out,
                           float* __restrict__ blocksum) {
  const int tid = threadIdx.x;
  const int token = blockIdx.x * 64 + (tid >> 2);
  const int part = tid & 3;

  const unsigned long long key = packed[token];
  const int bidx = (int)(unsigned int)key;

  float err = 0.0f;
  if (part == 0) {
    out[IDX_OFF + (size_t)token] = (float)bidx;
    unsigned int u = (unsigned int)(key >> 32);
    unsigned int fb = (u & 0x80000000u) ? (u ^ 0x80000000u) : ~u;
    err = __uint_as_float(fb);  // min distance == |x - e|^2 (expanded form)
  }

  const float4* eq = (const float4*)(emb + (size_t)bidx * DD) + part * 4;
  float4* op = (float4*)(out + (size_t)token * DD) + part * 4;
  float4 v0 = eq[0], v1 = eq[1], v2 = eq[2], v3 = eq[3];
  op[0] = v0; op[1] = v1; op[2] = v2; op[3] = v3;

#pragma unroll
  for (int off = 32; off > 0; off >>= 1) err += __shfl_down(err, off);
  __shared__ float wsum[4];
  const int wid = tid >> 6;
  if ((tid & 63) == 0) wsum[wid] = err;
  __syncthreads();
  if (tid == 0)
    blocksum[blockIdx.x] = (wsum[0] + wsum[1]) + (wsum[2] + wsum[3]);
}

// 1 block: reduce 2048 per-block partials -> loss
__global__ void vq_finish(const float* __restrict__ blocksum,
                          float* __restrict__ out) {
  const int tid = threadIdx.x;
  float s = 0.0f;
#pragma unroll
  for (int i = 0; i < COMBINE_BLOCKS / 256; ++i)
    s += blocksum[i * 256 + tid];
#pragma unroll
  for (int off = 32; off > 0; off >>= 1) s += __shfl_down(s, off);
  __shared__ float wsum[4];
  const int wid = tid >> 6;
  if ((tid & 63) == 0) wsum[wid] = s;
  __syncthreads();
  if (tid == 0) {
    float total = (wsum[0] + wsum[1]) + (wsum[2] + wsum[3]);
    float m = total / (float)QUANT_ELEMS;
    out[LOSS_OFF] = m + 0.25f * m;  // q_latent + COMMITMENT_COST * e_latent
  }
}

extern "C" void kernel_launch(void* const* d_in, const int* in_sizes, int n_in,
                              void* d_out, int out_size, void* d_ws, size_t ws_size,
                              hipStream_t stream) {
  const float* x = (const float*)d_in[0];
  const float* emb = (const float*)d_in[1];
  float* out = (float*)d_out;
  float* ws = (float*)d_ws;
  unsigned long long* packed = (unsigned long long*)(ws + WS_PACKED_F);

  vq_setup<<<580, 256, 0, stream>>>(x, emb, ws);
  dim3 gdist(NTOK / 256, NQ);
  vq_dist_mfma<<<gdist, 256, 0, stream>>>(x, ws, packed);
  vq_combine<<<COMBINE_BLOCKS, 256, 0, stream>>>(emb, packed, out, ws + WS_BSUM);
  vq_finish<<<1, 256, 0, stream>>>(ws + WS_BSUM, out);
}